// Round 5
// baseline (114.031 us; speedup 1.0000x reference)
//
#include <hip/hip_runtime.h>
#include <stdint.h>

#define W 768
#define NPROB (768*768)
#define NB 8
#define NBINS 2048
#define CAP 4096
#define TOPK 2048
#define SCORE_THR 0.6f
#define NBLK 72            // blocks per batch for scan kernels; NPROB = 72*8192
#define HASHN 8192
#define HEMPTY 0xFFFFFFFFu

// ws layout (bytes) — init_kernel zeroes hist; everything else written-before-read
#define HIST_OFF   0
#define HIST_BYTES (NB*NBINS*4)                 // 65536
#define META_OFF   (HIST_OFF + HIST_BYTES)
#define PFX_OFF    (META_OFF + 256)
#define PFX_BYTES  (NB*(NBINS+1)*4)             // 65568
#define CUR_OFF    (PFX_OFF + PFX_BYTES)
#define CUR_BYTES  (NB*NBINS*4)                 // 65536
#define CAND_OFF   (CUR_OFF + CUR_BYTES)
#define CAND_BYTES (NB*CAP*8)                   // 262144
#define WS_TOTAL   (CAND_OFF + CAND_BYTES)

struct Meta { unsigned bstar; unsigned cnt; unsigned pad0; unsigned pad1; };

// bin over float bits: valid scores are in [0.6,1.0) -> one binade, bits monotone
__device__ __forceinline__ unsigned score_bin(unsigned fb) {
    return (fb >> 13) & 0x7FFu;
}

__global__ __launch_bounds__(256) void init_kernel(unsigned* __restrict__ hist) {
    int i = blockIdx.x * 256 + threadIdx.x;
    if (i < NB * NBINS) hist[i] = 0;
}

// LDS histogram + one atomic merge per bin per block.
__global__ __launch_bounds__(256) void hist_kernel(const float* __restrict__ probs,
                                                   unsigned* __restrict__ hist) {
    __shared__ unsigned lh[NBINS];
    int b = blockIdx.y;
    for (int i = threadIdx.x; i < NBINS; i += 256) lh[i] = 0;
    __syncthreads();
    const int per4 = (NPROB / NBLK) / 4;      // 2048 float4 per block
    const float4* p = (const float4*)(probs + (size_t)b * NPROB) + (size_t)blockIdx.x * per4;
    for (int i = threadIdx.x; i < per4; i += 256) {
        float4 v = p[i];
        if (v.x >= SCORE_THR) atomicAdd(&lh[score_bin(__float_as_uint(v.x))], 1u);
        if (v.y >= SCORE_THR) atomicAdd(&lh[score_bin(__float_as_uint(v.y))], 1u);
        if (v.z >= SCORE_THR) atomicAdd(&lh[score_bin(__float_as_uint(v.z))], 1u);
        if (v.w >= SCORE_THR) atomicAdd(&lh[score_bin(__float_as_uint(v.w))], 1u);
    }
    __syncthreads();
    unsigned* gh = hist + b * NBINS;
    for (int i = threadIdx.x; i < NBINS; i += 256) {
        unsigned v = lh[i];
        if (v) atomicAdd(&gh[i], v);
    }
}

// Descending suffix-scan over bins: pfx[B] = #{scores in bins >= B}.
// Finds bstar (threshold bin), writes binpfx + cursors (bin segment starts).
__global__ __launch_bounds__(256) void select_kernel(const unsigned* __restrict__ hist,
                                                     Meta* __restrict__ meta,
                                                     unsigned* __restrict__ binpfx,
                                                     unsigned* __restrict__ cursor) {
    int b = blockIdx.x;
    __shared__ unsigned h[NBINS];
    __shared__ unsigned pfx[NBINS + 1];
    __shared__ unsigned csum[256];
    __shared__ unsigned sb;
    int t = threadIdx.x;
    for (int i = t; i < NBINS; i += 256) h[i] = hist[b * NBINS + i];
    if (t == 0) sb = 0;
    __syncthreads();
    unsigned s = 0;
    #pragma unroll
    for (int i = 0; i < 8; ++i) s += h[t * 8 + i];
    csum[t] = s;
    __syncthreads();
    // inclusive suffix sum across 256 chunks
    for (int off = 1; off < 256; off <<= 1) {
        unsigned v = (t + off < 256) ? csum[t + off] : 0u;
        __syncthreads();
        csum[t] += v;
        __syncthreads();
    }
    unsigned run = csum[t];           // sum over bins >= 8t
    #pragma unroll
    for (int i = 0; i < 8; ++i) {
        pfx[t * 8 + i] = run;
        run -= h[t * 8 + i];
    }
    if (t == 0) pfx[NBINS] = 0;
    __syncthreads();
    #pragma unroll
    for (int i = 0; i < 8; ++i) {
        int B = t * 8 + i;
        if (pfx[B] >= TOPK && pfx[B + 1] < TOPK) sb = (unsigned)B;  // unique writer
    }
    __syncthreads();
    if (t == 0) {
        unsigned bs = sb;
        unsigned n = pfx[bs];
        meta[b].bstar = bs;
        meta[b].cnt = n < CAP ? n : CAP;
    }
    for (int i = t; i < NBINS; i += 256) {
        binpfx[b * (NBINS + 1) + i] = pfx[i];
        cursor[b * NBINS + i] = pfx[i + 1];   // segment start for bin i
    }
    if (t == 0) binpfx[b * (NBINS + 1) + NBINS] = 0;
}

// Scatter candidates into bin-segmented cand[] via per-bin cursors.
__global__ __launch_bounds__(256) void compact_kernel(const float* __restrict__ probs,
                                                      const Meta* __restrict__ meta,
                                                      unsigned* __restrict__ cursor,
                                                      unsigned long long* __restrict__ cand) {
    int b = blockIdx.y;
    unsigned bstar = meta[b].bstar;
    const int per4 = (NPROB / NBLK) / 4;
    int base_elem = blockIdx.x * (NPROB / NBLK);
    const float4* p = (const float4*)(probs + (size_t)b * NPROB) + (size_t)blockIdx.x * per4;
    unsigned long long* dst = cand + (size_t)b * CAP;
    for (int i = threadIdx.x; i < per4; i += 256) {
        float4 v = p[i];
        int ei = base_elem + i * 4;
        float sv[4] = {v.x, v.y, v.z, v.w};
        #pragma unroll
        for (int c = 0; c < 4; ++c) {
            float s = sv[c];
            if (s >= SCORE_THR) {
                unsigned fb = __float_as_uint(s);
                unsigned B = score_bin(fb);
                if (B >= bstar) {
                    unsigned pos = atomicAdd(&cursor[b * NBINS + B], 1u);
                    if (pos < CAP) {
                        unsigned idx = (unsigned)(ei + c);
                        dst[pos] = ((unsigned long long)fb << 32) | (unsigned)(~idx);
                    }
                }
            }
        }
    }
}

// Fused: in-bin exact ranking (keys unique -> jax top_k order), LDS hash
// (cell->rank) neighbor discovery, monotone fixpoint NMS, refine + write.
__global__ __launch_bounds__(1024) void nms_out_kernel(const float* __restrict__ dev4,
                                                       const unsigned long long* __restrict__ cand,
                                                       const Meta* __restrict__ meta,
                                                       const unsigned* __restrict__ binpfx,
                                                       float* __restrict__ out) {
    int b = blockIdx.x;
    __shared__ unsigned long long k[CAP];     // 32 KB
    __shared__ unsigned s_pfx[NBINS + 1];     // 8.2 KB
    __shared__ unsigned s_hash[HASHN];        // 32 KB
    __shared__ unsigned char s_state[TOPK];   // 2 KB  0=und 1=kept 2=dead
    __shared__ int s_changed;
    int tid = threadIdx.x;

    int n = (int)meta[b].cnt;                 // <= CAP
    int nvalid = n < TOPK ? n : TOPK;

    int nload = (n + 1023) & ~1023;
    if (nload > CAP) nload = CAP;
    for (int i = tid; i < nload; i += 1024) k[i] = cand[(size_t)b * CAP + i];
    for (int i = tid; i <= NBINS; i += 1024) s_pfx[i] = binpfx[b * (NBINS + 1) + i];
    for (int i = tid; i < HASHN; i += 1024) s_hash[i] = HEMPTY;
    for (int i = tid; i < TOPK; i += 1024) s_state[i] = 2;
    __syncthreads();

    // phase B: rank each owned candidate within its bin segment; insert hash
    unsigned myr[4], myidx[4], myfb[4];
    #pragma unroll
    for (int q = 0; q < 4; ++q) {
        int p = tid + q * 1024;
        myr[q] = 0xFFFFFFFFu;
        if (p < n) {
            unsigned long long key = k[p];
            unsigned fb = (unsigned)(key >> 32);
            unsigned idx = ~(unsigned)key;
            unsigned B = score_bin(fb);
            int st = (int)s_pfx[B + 1];
            int en = (int)s_pfx[B]; if (en > n) en = n;
            int r = st;
            for (int i = st; i < en; ++i) r += (k[i] > key);
            if (r < TOPK) {
                myr[q] = (unsigned)r;
                myidx[q] = idx;
                myfb[q] = fb;
                unsigned val = (idx << 11) | (unsigned)r;
                unsigned slot = (idx * 2654435761u >> 19) & (HASHN - 1);
                while (true) {
                    unsigned old = atomicCAS(&s_hash[slot], HEMPTY, val);
                    if (old == HEMPTY) break;
                    slot = (slot + 1) & (HASHN - 1);
                }
            }
        }
    }
    __syncthreads();

    // phase C: neighbor discovery (8 cells, earlier ranks only), init state
    const int DY[8] = {-1,-1,-1, 0, 0, 1, 1, 1};
    const int DX[8] = {-1, 0, 1,-1, 1,-1, 0, 1};
    unsigned long long np0[4] = {0,0,0,0}, np1[4] = {0,0,0,0};
    int nc[4] = {0,0,0,0};
    #pragma unroll
    for (int q = 0; q < 4; ++q) {
        if (myr[q] != 0xFFFFFFFFu) {
            int y = (int)(myidx[q] / W), x = (int)(myidx[q] % W);
            int cnt2 = 0;
            unsigned long long l0 = 0, l1 = 0;
            #pragma unroll
            for (int t = 0; t < 8; ++t) {
                int ny = y + DY[t], nx = x + DX[t];
                if ((unsigned)ny < (unsigned)W && (unsigned)nx < (unsigned)W) {
                    unsigned cell = (unsigned)(ny * W + nx);
                    unsigned slot = (cell * 2654435761u >> 19) & (HASHN - 1);
                    int r = -1;
                    while (true) {
                        unsigned v = s_hash[slot];
                        if (v == HEMPTY) break;
                        if ((v >> 11) == cell) { r = (int)(v & 2047u); break; }
                        slot = (slot + 1) & (HASHN - 1);
                    }
                    if (r >= 0 && r < (int)myr[q]) {
                        if (cnt2 < 4) l0 |= (unsigned long long)(unsigned)r << (cnt2 * 16);
                        else          l1 |= (unsigned long long)(unsigned)r << ((cnt2 - 4) * 16);
                        cnt2++;
                    }
                }
            }
            np0[q] = l0; np1[q] = l1; nc[q] = cnt2;
            s_state[myr[q]] = (cnt2 == 0) ? 1 : 0;
        }
    }
    __syncthreads();

    // fixpoint: unique fixpoint == sequential greedy NMS
    while (true) {
        if (tid == 0) s_changed = 0;
        __syncthreads();
        bool ch = false;
        #pragma unroll
        for (int q = 0; q < 4; ++q) {
            if (myr[q] != 0xFFFFFFFFu && s_state[myr[q]] == 0) {
                bool anyKept = false, anyUnd = false;
                int c = nc[q];
                #pragma unroll
                for (int l = 0; l < 8; ++l) {
                    if (l < c) {
                        unsigned r = (l < 4)
                            ? (unsigned)((np0[q] >> (l * 16)) & 0xFFFFu)
                            : (unsigned)((np1[q] >> ((l - 4) * 16)) & 0xFFFFu);
                        unsigned char st = s_state[r];
                        anyKept |= (st == 1);
                        anyUnd  |= (st == 0);
                    }
                }
                if (anyKept)      { s_state[myr[q]] = 2; ch = true; }
                else if (!anyUnd) { s_state[myr[q]] = 1; ch = true; }
            }
        }
        if (ch) s_changed = 1;
        __syncthreads();
        if (s_changed == 0) break;
        __syncthreads();
    }

    // output: zero tail rows, then one row per rank from its owner
    for (int j = nvalid + tid; j < TOPK; j += 1024) {
        float* op = out + ((size_t)b * TOPK + j) * 5;
        op[0] = 0.f; op[1] = 0.f; op[2] = 0.f; op[3] = 0.f; op[4] = 0.f;
    }
    #pragma unroll
    for (int q = 0; q < 4; ++q) {
        if (myr[q] != 0xFFFFFFFFu) {
            unsigned r = myr[q];
            float o0 = 0.f, o1 = 0.f, o2 = 0.f, o3 = 0.f, o4 = 0.f;
            if (s_state[r] == 1) {
                unsigned idx = myidx[q];
                float sc = __uint_as_float(myfb[q]);
                int y = (int)(idx / W), x = (int)(idx % W);
                const float4 d = ((const float4*)dev4)[(size_t)b * NPROB + idx];
                float b0 = (float)(4 * y + 2);
                float b1 = (float)(4 * x + 2);
                float b2 = (float)(4 * y + 24);
                float b3 = (float)(4 * x + 24);
                float r0 = b0 + d.x * 22.0f;
                float r1 = b1 + d.y * 22.0f;
                float r2 = b2 + d.z * 22.0f;
                float r3 = b3 + d.w * 22.0f;
                float rh = r2 - r0, rw = r3 - r1;
                float len = fmaxf(rh, rw);
                float c0 = r0 + rh * 0.5f, c1v = r1 + rw * 0.5f;
                float u0 = c0 - 0.5f * len, u1 = c1v - 0.5f * len;
                float v0 = u0 + len, v1 = u1 + len;
                o0 = fminf(fmaxf(u0, 1.0f), 3095.0f);
                o1 = fminf(fmaxf(u1, 1.0f), 3095.0f);
                o2 = fminf(fmaxf(v0, 1.0f), 3095.0f);
                o3 = fminf(fmaxf(v1, 1.0f), 3095.0f);
                o4 = sc;
            }
            float* op = out + ((size_t)b * TOPK + r) * 5;
            op[0] = o0; op[1] = o1; op[2] = o2; op[3] = o3; op[4] = o4;
        }
    }
}

extern "C" void kernel_launch(void* const* d_in, const int* in_sizes, int n_in,
                              void* d_out, int out_size, void* d_ws, size_t ws_size,
                              hipStream_t stream) {
    (void)in_sizes; (void)n_in; (void)out_size;
    if (ws_size < (size_t)WS_TOTAL) return;

    const float* probs = (const float*)d_in[0];
    const float* devs  = (const float*)d_in[1];
    float* out = (float*)d_out;
    char* ws = (char*)d_ws;

    unsigned* hist = (unsigned*)(ws + HIST_OFF);
    Meta* meta = (Meta*)(ws + META_OFF);
    unsigned* binpfx = (unsigned*)(ws + PFX_OFF);
    unsigned* cursor = (unsigned*)(ws + CUR_OFF);
    unsigned long long* cand = (unsigned long long*)(ws + CAND_OFF);

    init_kernel<<<(NB * NBINS + 255) / 256, 256, 0, stream>>>(hist);
    hist_kernel<<<dim3(NBLK, NB), 256, 0, stream>>>(probs, hist);
    select_kernel<<<NB, 256, 0, stream>>>(hist, meta, binpfx, cursor);
    compact_kernel<<<dim3(NBLK, NB), 256, 0, stream>>>(probs, meta, cursor, cand);
    nms_out_kernel<<<NB, 1024, 0, stream>>>(devs, cand, meta, binpfx, out);
}

// Round 6
// 92.986 us; speedup vs baseline: 1.2263x; 1.2263x over previous
//
#include <hip/hip_runtime.h>
#include <stdint.h>

#define W 768
#define NPROB (768*768)
#define NB 8
#define NBINS 2048
#define CAP 4096
#define TOPK 2048
#define SCORE_THR 0.6f
#define NBLK 72            // blocks per batch for scan kernels; NPROB = 72*8192

// ws layout (bytes) — init_kernel handles map+hist; rest written-before-read
#define MAP_OFF    0
#define MAP_BYTES  (NB*NPROB*2)                 // 9,437,184
#define HIST_OFF   (MAP_OFF + MAP_BYTES)
#define HIST_BYTES (NB*NBINS*4)                 // 65,536
#define META_OFF   (HIST_OFF + HIST_BYTES)
#define PFX_OFF    (META_OFF + 256)
#define PFX_BYTES  (NB*(NBINS+1)*4)             // 65,568
#define CUR_OFF    (PFX_OFF + PFX_BYTES)
#define CUR_BYTES  (NB*NBINS*4)                 // 65,536
#define CAND_OFF   (CUR_OFF + CUR_BYTES)
#define CAND_BYTES (NB*CAP*8)                   // 262,144
#define SKEY_OFF   (CAND_OFF + CAND_BYTES)
#define SKEY_BYTES (NB*TOPK*8)                  // 131,072
#define KEEP_OFF   (SKEY_OFF + SKEY_BYTES)
#define KEEP_BYTES (NB*TOPK)                    // 16,384
#define WS_TOTAL   (KEEP_OFF + KEEP_BYTES)

#define MAP_U4  (MAP_BYTES/16)                  // 589,824
#define HIST_U4 (HIST_BYTES/16)                 // 4,096
#define INIT_U4 (MAP_U4 + HIST_U4)

struct Meta { unsigned bstar; unsigned cnt; unsigned pad0; unsigned pad1; };

// bin over float bits: valid scores are in [0.6,1.0) -> one binade, bits monotone
__device__ __forceinline__ unsigned score_bin(unsigned fb) {
    return (fb >> 13) & 0x7FFu;
}

// Fill cellmap with 0xFFFF and zero hist; one wide streaming kernel.
__global__ __launch_bounds__(256) void init_kernel(uint4* __restrict__ map,
                                                   uint4* __restrict__ hist) {
    int i = blockIdx.x * 256 + threadIdx.x;
    if (i < MAP_U4) map[i] = make_uint4(~0u, ~0u, ~0u, ~0u);
    else if (i < INIT_U4) hist[i - MAP_U4] = make_uint4(0u, 0u, 0u, 0u);
}

// LDS histogram + one atomic merge per bin per block.
__global__ __launch_bounds__(256) void hist_kernel(const float* __restrict__ probs,
                                                   unsigned* __restrict__ hist) {
    __shared__ unsigned lh[NBINS];
    int b = blockIdx.y;
    for (int i = threadIdx.x; i < NBINS; i += 256) lh[i] = 0;
    __syncthreads();
    const int per4 = (NPROB / NBLK) / 4;      // 2048 float4 per block
    const float4* p = (const float4*)(probs + (size_t)b * NPROB) + (size_t)blockIdx.x * per4;
    for (int i = threadIdx.x; i < per4; i += 256) {
        float4 v = p[i];
        if (v.x >= SCORE_THR) atomicAdd(&lh[score_bin(__float_as_uint(v.x))], 1u);
        if (v.y >= SCORE_THR) atomicAdd(&lh[score_bin(__float_as_uint(v.y))], 1u);
        if (v.z >= SCORE_THR) atomicAdd(&lh[score_bin(__float_as_uint(v.z))], 1u);
        if (v.w >= SCORE_THR) atomicAdd(&lh[score_bin(__float_as_uint(v.w))], 1u);
    }
    __syncthreads();
    unsigned* gh = hist + b * NBINS;
    for (int i = threadIdx.x; i < NBINS; i += 256) {
        unsigned v = lh[i];
        if (v) atomicAdd(&gh[i], v);
    }
}

// Descending suffix-scan over bins: pfx[B] = #{scores in bins >= B}.
__global__ __launch_bounds__(256) void select_kernel(const unsigned* __restrict__ hist,
                                                     Meta* __restrict__ meta,
                                                     unsigned* __restrict__ binpfx,
                                                     unsigned* __restrict__ cursor) {
    int b = blockIdx.x;
    __shared__ unsigned h[NBINS];
    __shared__ unsigned pfx[NBINS + 1];
    __shared__ unsigned csum[256];
    __shared__ unsigned sb;
    int t = threadIdx.x;
    for (int i = t; i < NBINS; i += 256) h[i] = hist[b * NBINS + i];
    if (t == 0) sb = 0;
    __syncthreads();
    unsigned s = 0;
    #pragma unroll
    for (int i = 0; i < 8; ++i) s += h[t * 8 + i];
    csum[t] = s;
    __syncthreads();
    for (int off = 1; off < 256; off <<= 1) {
        unsigned v = (t + off < 256) ? csum[t + off] : 0u;
        __syncthreads();
        csum[t] += v;
        __syncthreads();
    }
    unsigned run = csum[t];           // sum over bins >= 8t
    #pragma unroll
    for (int i = 0; i < 8; ++i) {
        pfx[t * 8 + i] = run;
        run -= h[t * 8 + i];
    }
    if (t == 0) pfx[NBINS] = 0;
    __syncthreads();
    #pragma unroll
    for (int i = 0; i < 8; ++i) {
        int B = t * 8 + i;
        if (pfx[B] >= TOPK && pfx[B + 1] < TOPK) sb = (unsigned)B;  // unique writer
    }
    __syncthreads();
    if (t == 0) {
        unsigned bs = sb;
        unsigned n = pfx[bs];
        meta[b].bstar = bs;
        meta[b].cnt = n < CAP ? n : CAP;
    }
    for (int i = t; i < NBINS; i += 256) {
        binpfx[b * (NBINS + 1) + i] = pfx[i];
        cursor[b * NBINS + i] = pfx[i + 1];   // segment start for bin i
    }
    if (t == 0) binpfx[b * (NBINS + 1) + NBINS] = 0;
}

// Scatter candidates into bin-segmented cand[] via per-bin cursors.
__global__ __launch_bounds__(256) void compact_kernel(const float* __restrict__ probs,
                                                      const Meta* __restrict__ meta,
                                                      unsigned* __restrict__ cursor,
                                                      unsigned long long* __restrict__ cand) {
    int b = blockIdx.y;
    unsigned bstar = meta[b].bstar;
    const int per4 = (NPROB / NBLK) / 4;
    int base_elem = blockIdx.x * (NPROB / NBLK);
    const float4* p = (const float4*)(probs + (size_t)b * NPROB) + (size_t)blockIdx.x * per4;
    unsigned long long* dst = cand + (size_t)b * CAP;
    for (int i = threadIdx.x; i < per4; i += 256) {
        float4 v = p[i];
        int ei = base_elem + i * 4;
        float sv[4] = {v.x, v.y, v.z, v.w};
        #pragma unroll
        for (int c = 0; c < 4; ++c) {
            float s = sv[c];
            if (s >= SCORE_THR) {
                unsigned fb = __float_as_uint(s);
                unsigned B = score_bin(fb);
                if (B >= bstar) {
                    unsigned pos = atomicAdd(&cursor[b * NBINS + B], 1u);
                    if (pos < CAP) {
                        unsigned idx = (unsigned)(ei + c);
                        dst[pos] = ((unsigned long long)fb << 32) | (unsigned)(~idx);
                    }
                }
            }
        }
    }
}

// Wide exact ranking: thread p ranks candidate p by scanning ONLY its bin
// segment (~115 elems). Unique keys -> exact jax top_k order. Writes
// skey[rank] and cellmap[cell]=rank (race-free: cell indices unique).
__global__ __launch_bounds__(256) void rank_kernel(const unsigned long long* __restrict__ cand,
                                                   const Meta* __restrict__ meta,
                                                   const unsigned* __restrict__ binpfx,
                                                   unsigned long long* __restrict__ skey,
                                                   unsigned short* __restrict__ cellmap) {
    int b = blockIdx.y;
    __shared__ unsigned long long k[CAP];     // 32 KB
    __shared__ unsigned s_pfx[NBINS + 1];     // 8.2 KB
    int n = (int)meta[b].cnt;                 // <= CAP
    int nload = (n + 255) & ~255;
    if (nload > CAP) nload = CAP;
    for (int i = threadIdx.x; i < nload; i += 256) k[i] = cand[(size_t)b * CAP + i];
    for (int i = threadIdx.x; i <= NBINS; i += 256) s_pfx[i] = binpfx[b * (NBINS + 1) + i];
    __syncthreads();
    int p = blockIdx.x * 256 + threadIdx.x;
    if (p < n) {
        unsigned long long key = k[p];
        unsigned fb = (unsigned)(key >> 32);
        unsigned idx = ~(unsigned)key;
        unsigned B = score_bin(fb);
        int st = (int)s_pfx[B + 1];
        int en = (int)s_pfx[B]; if (en > n) en = n;
        int r = st;
        for (int i = st; i < en; ++i) r += (k[i] > key);
        if (r < TOPK) {
            skey[(size_t)b * TOPK + r] = key;
            cellmap[(size_t)b * NPROB + idx] = (unsigned short)r;
        }
    }
}

// Per-batch: neighbor discovery via 8 cellmap loads, 2KB-LDS fixpoint, keep[].
__global__ __launch_bounds__(1024) void fix_kernel(const unsigned long long* __restrict__ skey,
                                                   const Meta* __restrict__ meta,
                                                   const unsigned short* __restrict__ cellmap,
                                                   unsigned char* __restrict__ keep) {
    int b = blockIdx.x;
    __shared__ unsigned char s_state[TOPK];   // 0=und 1=kept 2=dead
    __shared__ int s_changed;
    int tid = threadIdx.x;
    unsigned cnt = meta[b].cnt;
    int nvalid = (int)(cnt < TOPK ? cnt : TOPK);

    const int DY[8] = {-1,-1,-1, 0, 0, 1, 1, 1};
    const int DX[8] = {-1, 0, 1,-1, 1,-1, 0, 1};
    unsigned long long np0[2] = {0,0}, np1[2] = {0,0};
    int nc[2] = {0,0};
    bool vld[2];
    const unsigned short* cm = cellmap + (size_t)b * NPROB;
    #pragma unroll 2
    for (int q = 0; q < 2; ++q) {
        int r = tid + q * 1024;
        vld[q] = (r < nvalid);
        if (vld[q]) {
            unsigned long long key = skey[(size_t)b * TOPK + r];
            unsigned idx = ~(unsigned)key;
            int y = (int)(idx / W), x = (int)(idx % W);
            int c2 = 0;
            unsigned long long l0 = 0, l1 = 0;
            #pragma unroll
            for (int t = 0; t < 8; ++t) {
                int ny = y + DY[t], nx = x + DX[t];
                if ((unsigned)ny < (unsigned)W && (unsigned)nx < (unsigned)W) {
                    unsigned rr = cm[ny * W + nx];
                    if (rr != 0xFFFFu && (int)rr < r) {
                        if (c2 < 4) l0 |= (unsigned long long)rr << (c2 * 16);
                        else        l1 |= (unsigned long long)rr << ((c2 - 4) * 16);
                        c2++;
                    }
                }
            }
            np0[q] = l0; np1[q] = l1; nc[q] = c2;
            s_state[r] = (c2 == 0) ? 1 : 0;
        } else if (r < TOPK) {
            s_state[r] = 2;
        }
    }
    __syncthreads();

    while (true) {
        if (tid == 0) s_changed = 0;
        __syncthreads();
        bool ch = false;
        #pragma unroll 2
        for (int q = 0; q < 2; ++q) {
            int r = tid + q * 1024;
            if (vld[q] && s_state[r] == 0) {
                bool anyKept = false, anyUnd = false;
                int c = nc[q];
                #pragma unroll
                for (int l = 0; l < 8; ++l) {
                    if (l < c) {
                        unsigned rr = (l < 4)
                            ? (unsigned)((np0[q] >> (l * 16)) & 0xFFFFu)
                            : (unsigned)((np1[q] >> ((l - 4) * 16)) & 0xFFFFu);
                        unsigned char st = s_state[rr];
                        anyKept |= (st == 1);
                        anyUnd  |= (st == 0);
                    }
                }
                if (anyKept)      { s_state[r] = 2; ch = true; }
                else if (!anyUnd) { s_state[r] = 1; ch = true; }
            }
        }
        if (ch) s_changed = 1;
        __syncthreads();
        if (s_changed == 0) break;
        __syncthreads();
    }

    #pragma unroll 2
    for (int q = 0; q < 2; ++q) {
        int r = tid + q * 1024;
        if (r < TOPK) keep[(size_t)b * TOPK + r] = (s_state[r] == 1) ? 1 : 0;
    }
}

// Wide output: one thread per output row; gather dev4 only for kept rows.
__global__ __launch_bounds__(256) void out_kernel(const float* __restrict__ dev4,
                                                  const unsigned long long* __restrict__ skey,
                                                  const unsigned char* __restrict__ keep,
                                                  float* __restrict__ out) {
    int b = blockIdx.y;
    int r = blockIdx.x * 256 + threadIdx.x;
    float o0 = 0.f, o1 = 0.f, o2 = 0.f, o3 = 0.f, o4 = 0.f;
    if (keep[(size_t)b * TOPK + r]) {
        unsigned long long key = skey[(size_t)b * TOPK + r];
        unsigned idx = ~(unsigned)key;
        float sc = __uint_as_float((unsigned)(key >> 32));
        int y = (int)(idx / W), x = (int)(idx % W);
        const float4 d = ((const float4*)dev4)[(size_t)b * NPROB + idx];
        float b0 = (float)(4 * y + 2);
        float b1 = (float)(4 * x + 2);
        float b2 = (float)(4 * y + 24);
        float b3 = (float)(4 * x + 24);
        float r0 = b0 + d.x * 22.0f;
        float r1 = b1 + d.y * 22.0f;
        float r2 = b2 + d.z * 22.0f;
        float r3 = b3 + d.w * 22.0f;
        float rh = r2 - r0, rw = r3 - r1;
        float len = fmaxf(rh, rw);
        float c0 = r0 + rh * 0.5f, c1v = r1 + rw * 0.5f;
        float u0 = c0 - 0.5f * len, u1 = c1v - 0.5f * len;
        float v0 = u0 + len, v1 = u1 + len;
        o0 = fminf(fmaxf(u0, 1.0f), 3095.0f);
        o1 = fminf(fmaxf(u1, 1.0f), 3095.0f);
        o2 = fminf(fmaxf(v0, 1.0f), 3095.0f);
        o3 = fminf(fmaxf(v1, 1.0f), 3095.0f);
        o4 = sc;
    }
    float* op = out + ((size_t)b * TOPK + r) * 5;
    op[0] = o0; op[1] = o1; op[2] = o2; op[3] = o3; op[4] = o4;
}

extern "C" void kernel_launch(void* const* d_in, const int* in_sizes, int n_in,
                              void* d_out, int out_size, void* d_ws, size_t ws_size,
                              hipStream_t stream) {
    (void)in_sizes; (void)n_in; (void)out_size;
    if (ws_size < (size_t)WS_TOTAL) return;

    const float* probs = (const float*)d_in[0];
    const float* devs  = (const float*)d_in[1];
    float* out = (float*)d_out;
    char* ws = (char*)d_ws;

    unsigned short* cellmap = (unsigned short*)(ws + MAP_OFF);
    unsigned* hist = (unsigned*)(ws + HIST_OFF);
    Meta* meta = (Meta*)(ws + META_OFF);
    unsigned* binpfx = (unsigned*)(ws + PFX_OFF);
    unsigned* cursor = (unsigned*)(ws + CUR_OFF);
    unsigned long long* cand = (unsigned long long*)(ws + CAND_OFF);
    unsigned long long* skey = (unsigned long long*)(ws + SKEY_OFF);
    unsigned char* keep = (unsigned char*)(ws + KEEP_OFF);

    init_kernel<<<(INIT_U4 + 255) / 256, 256, 0, stream>>>((uint4*)cellmap, (uint4*)hist);
    hist_kernel<<<dim3(NBLK, NB), 256, 0, stream>>>(probs, hist);
    select_kernel<<<NB, 256, 0, stream>>>(hist, meta, binpfx, cursor);
    compact_kernel<<<dim3(NBLK, NB), 256, 0, stream>>>(probs, meta, cursor, cand);
    rank_kernel<<<dim3(CAP / 256, NB), 256, 0, stream>>>(cand, meta, binpfx, skey, cellmap);
    fix_kernel<<<NB, 1024, 0, stream>>>(skey, meta, cellmap, keep);
    out_kernel<<<dim3(TOPK / 256, NB), 256, 0, stream>>>(devs, skey, keep, out);
}